// Round 1
// baseline (214.116 us; speedup 1.0000x reference)
//
#include <hip/hip_runtime.h>
#include <hip/hip_bf16.h>

#define B_ 32
#define N_ 512
#define H_ 128

typedef float f32x4 __attribute__((ext_vector_type(4)));
typedef short short8 __attribute__((ext_vector_type(8)));
typedef short short4v __attribute__((ext_vector_type(4)));

static __device__ __forceinline__ float bf2f(unsigned short u) {
  union { unsigned int ui; float f; } x;
  x.ui = ((unsigned int)u) << 16;
  return x.f;
}
static __device__ __forceinline__ unsigned short f2bf(float f) {
  __hip_bfloat16 h = __float2bfloat16(f);
  return *reinterpret_cast<unsigned short*>(&h);
}

// -------------------------------------------------------------------------
// Kernel 1: h[b,n,d] = silu(LN(s[b,n,:] @ W1[d,:] + b1[d]))
// stored TRANSPOSED bf16 into ws:  h_t[b][d][n]  (n contiguous, k-major for
// the MFMA B-operand of kernel 2).
// Grid: (N/32, B), block 256. Tile: 32 n-rows x 128 d.
// Thread (a = t&15, g = t>>4): owns d = dd*16+a (dd<8), n = nn*16+g (nn<2).
// -------------------------------------------------------------------------
__global__ __launch_bounds__(256) void lin_ln_silu_kernel(
    const float* __restrict__ s, const float* __restrict__ W1,
    const float* __restrict__ b1, unsigned short* __restrict__ h_t) {
  __shared__ float s_sh[32 * 132];            // [n][k] fp32, pad 132
  __shared__ unsigned short w_sh[128 * 132];  // [d][k] bf16, pad 132
  __shared__ unsigned short ht_sh[128 * 40];  // [d][n] bf16, pad 40
  const int t = threadIdx.x;
  const int b = blockIdx.y;
  const int n0 = blockIdx.x * 32;

  // stage W1 (128x128) fp32 -> bf16 LDS, coalesced float4 reads
#pragma unroll
  for (int r = 0; r < 16; ++r) {
    int q = t + 256 * r;
    int d = q >> 5, part = q & 31;
    float4 v = *reinterpret_cast<const float4*>(W1 + d * H_ + part * 4);
    short4v w;
    w.x = (short)f2bf(v.x); w.y = (short)f2bf(v.y);
    w.z = (short)f2bf(v.z); w.w = (short)f2bf(v.w);
    *reinterpret_cast<short4v*>(&w_sh[d * 132 + part * 4]) = w;
  }
  // stage s tile (32x128 fp32)
#pragma unroll
  for (int r = 0; r < 4; ++r) {
    int q = t + 256 * r;
    int n = q >> 5, part = q & 31;
    float4 v = *reinterpret_cast<const float4*>(
        s + ((size_t)b * N_ + n0 + n) * H_ + part * 4);
    *reinterpret_cast<float4*>(&s_sh[n * 132 + part * 4]) = v;
  }
  __syncthreads();

  const int a = t & 15;
  const int g = t >> 4;
  float acc[2][8];
#pragma unroll
  for (int nn = 0; nn < 2; ++nn)
#pragma unroll
    for (int dd = 0; dd < 8; ++dd) acc[nn][dd] = 0.f;

  float bias[8];
#pragma unroll
  for (int dd = 0; dd < 8; ++dd) bias[dd] = b1[dd * 16 + a];

  for (int k = 0; k < 128; k += 4) {
    float wf[8][4];
#pragma unroll
    for (int dd = 0; dd < 8; ++dd) {
      short4v wv =
          *reinterpret_cast<const short4v*>(&w_sh[(dd * 16 + a) * 132 + k]);
      wf[dd][0] = bf2f((unsigned short)wv.x);
      wf[dd][1] = bf2f((unsigned short)wv.y);
      wf[dd][2] = bf2f((unsigned short)wv.z);
      wf[dd][3] = bf2f((unsigned short)wv.w);
    }
#pragma unroll
    for (int nn = 0; nn < 2; ++nn) {
      float4 sv =
          *reinterpret_cast<const float4*>(&s_sh[(nn * 16 + g) * 132 + k]);
#pragma unroll
      for (int dd = 0; dd < 8; ++dd) {
        acc[nn][dd] += sv.x * wf[dd][0] + sv.y * wf[dd][1] +
                       sv.z * wf[dd][2] + sv.w * wf[dd][3];
      }
    }
  }

  // bias + LayerNorm over d (128) per n-row (16 lanes x 8 d each) + SiLU
#pragma unroll
  for (int nn = 0; nn < 2; ++nn) {
    float s1 = 0.f, s2 = 0.f;
#pragma unroll
    for (int dd = 0; dd < 8; ++dd) {
      float x = acc[nn][dd] + bias[dd];
      acc[nn][dd] = x;
      s1 += x;
      s2 += x * x;
    }
#pragma unroll
    for (int off = 8; off >= 1; off >>= 1) {
      s1 += __shfl_xor(s1, off);
      s2 += __shfl_xor(s2, off);
    }
    float mean = s1 * (1.f / 128.f);
    float var = s2 * (1.f / 128.f) - mean * mean;
    float rs = rsqrtf(var + 1e-5f);
#pragma unroll
    for (int dd = 0; dd < 8; ++dd) {
      float x = (acc[nn][dd] - mean) * rs;
      float y = x / (1.f + __expf(-x));  // silu
      ht_sh[(dd * 16 + a) * 40 + nn * 16 + g] = f2bf(y);
    }
  }
  __syncthreads();

  // coalesced copy-out: 128 d-rows x 32 n (64 B/row)
#pragma unroll
  for (int r = 0; r < 2; ++r) {
    int q = t + 256 * r;
    int d = q >> 2, part = q & 3;
    float4 v = *reinterpret_cast<const float4*>(&ht_sh[d * 40 + part * 8]);
    *reinterpret_cast<float4*>(
        h_t + ((size_t)b * 128 + d) * 512 + n0 + part * 8) = v;
  }
}

// -------------------------------------------------------------------------
// Kernel 2: v[b,i,c,d] = sum_j mask[b,i,j]*ev[b,i,j,c]*h[b,j,d]  via MFMA.
// Per block: b, 16 i's. M-tile = 48 (m = c*16+il), N = 128 (d), K = 512 (j).
// Per 64-j round: stage h_t tile [d][j] and A-tile ph[m][j] (bf16) in LDS,
// then 2 k-slabs x (3 m-tiles x 2 n-tiles)/wave of mfma_f32_16x16x32_bf16.
// Grid: (N/16, B), block 256 (4 waves; wave w covers d in [w*32, w*32+32)).
// -------------------------------------------------------------------------
__global__ __launch_bounds__(256) void cfconv_mfma_kernel(
    const float* __restrict__ ev, const float* __restrict__ mask,
    const unsigned short* __restrict__ h_t, float* __restrict__ out) {
  __shared__ unsigned short ph[48 * 72];   // [m=c*16+il][j] bf16, pad 72
  __shared__ unsigned short hh[128 * 72];  // [d][j] bf16, pad 72
  const int t = threadIdx.x;
  const int b = blockIdx.y;
  const int i0 = blockIdx.x * 16;
  const int lane = t & 63;
  const int w = t >> 6;
  const int l15 = lane & 15;
  const int quad = lane >> 4;

  f32x4 acc[3][2];
#pragma unroll
  for (int mt = 0; mt < 3; ++mt)
#pragma unroll
    for (int nt = 0; nt < 2; ++nt)
#pragma unroll
      for (int e = 0; e < 4; ++e) acc[mt][nt][e] = 0.f;

  for (int j0 = 0; j0 < N_; j0 += 64) {
    __syncthreads();  // previous round's readers done before overwrite

    // stage hh: 128 d-rows x 64 j bf16 (128 B/row), 16 B chunks
#pragma unroll
    for (int r = 0; r < 4; ++r) {
      int q = t + 256 * r;
      int d = q >> 3, p8 = q & 7;
      float4 v = *reinterpret_cast<const float4*>(
          h_t + ((size_t)b * 128 + d) * 512 + j0 + p8 * 8);
      *reinterpret_cast<float4*>(&hh[d * 72 + p8 * 8]) = v;
    }

    // stage ph: ev (coalesced float4) * mask (global, L1-dedup) -> bf16
#pragma unroll
    for (int r = 0; r < 3; ++r) {
      int q = t + 256 * r;          // 0..767
      int i = q / 48, part = q % 48;
      int f0 = part * 4;
      const float* evbase =
          ev + ((size_t)((b * N_ + i0 + i)) * N_ + j0) * 3;
      float4 e4 = *reinterpret_cast<const float4*>(evbase + f0);
      const float* mrow = mask + (size_t)(b * N_ + i0 + i) * N_ + j0;
      int jlo = f0 / 3, jhi = (f0 + 3) / 3;
      float mlo = mrow[jlo], mhi = mrow[jhi];
      float evv[4] = {e4.x, e4.y, e4.z, e4.w};
#pragma unroll
      for (int e = 0; e < 4; ++e) {
        int f = f0 + e;
        int j = f / 3, c = f - 3 * j;
        float m = (j == jlo) ? mlo : mhi;
        ph[(c * 16 + i) * 72 + j] = f2bf(evv[e] * m);
      }
    }
    __syncthreads();

    // compute: 2 k-slabs of 32
#pragma unroll
    for (int ks = 0; ks < 2; ++ks) {
      short8 av[3], bv[2];
#pragma unroll
      for (int mt = 0; mt < 3; ++mt)
        av[mt] = *reinterpret_cast<const short8*>(
            &ph[(mt * 16 + l15) * 72 + ks * 32 + quad * 8]);
#pragma unroll
      for (int nt = 0; nt < 2; ++nt) {
        int d = w * 32 + nt * 16 + l15;
        bv[nt] = *reinterpret_cast<const short8*>(
            &hh[d * 72 + ks * 32 + quad * 8]);
      }
#pragma unroll
      for (int mt = 0; mt < 3; ++mt)
#pragma unroll
        for (int nt = 0; nt < 2; ++nt)
          acc[mt][nt] = __builtin_amdgcn_mfma_f32_16x16x32_bf16(
              av[mt], bv[nt], acc[mt][nt], 0, 0, 0);
    }
  }

  // epilogue: C/D layout col=lane&15 (d), row=quad*4+reg (il); c = mt
#pragma unroll
  for (int mt = 0; mt < 3; ++mt) {
#pragma unroll
    for (int nt = 0; nt < 2; ++nt) {
      int d = w * 32 + nt * 16 + l15;
#pragma unroll
      for (int r = 0; r < 4; ++r) {
        int i = i0 + quad * 4 + r;
        out[(((size_t)b * N_ + i) * 3 + mt) * H_ + d] = acc[mt][nt][r];
      }
    }
  }
}

extern "C" void kernel_launch(void* const* d_in, const int* in_sizes, int n_in,
                              void* d_out, int out_size, void* d_ws,
                              size_t ws_size, hipStream_t stream) {
  const float* s = (const float*)d_in[0];
  const float* ev = (const float*)d_in[1];
  const float* mask = (const float*)d_in[2];
  const float* W1 = (const float*)d_in[3];
  const float* b1 = (const float*)d_in[4];
  float* out = (float*)d_out;
  // ws: h_t bf16 [B][128 d][512 n] = 4 MB
  unsigned short* h_t = (unsigned short*)d_ws;

  lin_ln_silu_kernel<<<dim3(N_ / 32, B_), 256, 0, stream>>>(s, W1, b1, h_t);
  cfconv_mfma_kernel<<<dim3(N_ / 16, B_), 256, 0, stream>>>(ev, mask, h_t, out);
}